// Round 10
// baseline (678.555 us; speedup 1.0000x reference)
//
#include <hip/hip_runtime.h>
#include <hip/hip_bf16.h>
#include <stdint.h>

#define F 256            // IN_F == OUT_F == 256
#define KSTEP 32
#define CAP 64           // bucket slots per node (Poisson(32): P(deg>=64)~2e-7)
#define OVMAX 200000     // overflow list capacity

typedef short bhalf8 __attribute__((ext_vector_type(8)));
typedef unsigned short ushort8v __attribute__((ext_vector_type(8)));
typedef float f32x4 __attribute__((ext_vector_type(4)));
typedef int i32x4 __attribute__((ext_vector_type(4)));
typedef unsigned int u32x2 __attribute__((ext_vector_type(2)));

__device__ __forceinline__ unsigned short f2b(float f) {
    union { float f; uint32_t u; } x; x.f = f;
    uint32_t u = x.u;
    return (unsigned short)((u + 0x7FFFu + ((u >> 16) & 1u)) >> 16);
}
__device__ __forceinline__ float b2f(unsigned short h) {
    union { uint32_t u; float f; } x; x.u = ((uint32_t)h) << 16;
    return x.f;
}

// ---------------------------------------------------------------------------
// setup: blocks [0,98) zero count (+ overflow counter); [98,114) W-prep
// (f32 W[k][n] -> bf16 pre-tiled per K-step: Wt[sel][ks][n][kk])
// ---------------------------------------------------------------------------
__global__ __launch_bounds__(256) void setup_kernel(
    const float* __restrict__ Wm, const float* __restrict__ Wv,
    unsigned short* __restrict__ Wt, int* __restrict__ count,
    int* __restrict__ ovcnt, int N)
{
    if (blockIdx.x < 98) {
        if (blockIdx.x == 0 && threadIdx.x == 0) *ovcnt = 0;
        int gi = blockIdx.x * 1024 + threadIdx.x * 4;
        #pragma unroll
        for (int q = 0; q < 4; ++q)
            if (gi + q < N) count[gi + q] = 0;
        return;
    }
    int idx = (blockIdx.x - 98) * 256 + threadIdx.x;
    int sel = idx >> 11;
    int ks  = (idx >> 8) & 7;
    int n   = idx & 255;
    const float* W = sel ? Wv : Wm;
    unsigned short* dst = Wt + ((size_t)sel * 8 * 256 * 32) + ((size_t)(ks * 256 + n) * 32);
    #pragma unroll
    for (int kk = 0; kk < 32; ++kk)
        dst[kk] = f2b(W[(ks * 32 + kk) * 256 + n]);
}

// ---------------------------------------------------------------------------
// Dense tile body (R2-proven double-staged version).
// ---------------------------------------------------------------------------
__device__ __forceinline__ void dense_tile(
    const float* __restrict__ mean, const float* __restrict__ var,
    const unsigned short* __restrict__ Wt,
    const float* __restrict__ bm, const float* __restrict__ bv,
    unsigned short* __restrict__ mv, int N, int dbid,
    unsigned short (*Asm)[40], unsigned short (*Asv)[40],
    unsigned short (*Bsm)[40], unsigned short (*Bsv)[40])
{
    const int tid  = threadIdx.x;
    const int row0 = dbid * 64;
    const int lane = tid & 63;
    const int w    = tid >> 6;
    const int wr   = w >> 2;
    const int wc   = w & 3;
    const int lr   = lane & 15;
    const int lk   = lane >> 4;

    f32x4 accm[2][4], accv[2][4];
    #pragma unroll
    for (int i = 0; i < 2; ++i)
        #pragma unroll
        for (int j = 0; j < 4; ++j) { accm[i][j] = (f32x4)0.f; accv[i][j] = (f32x4)0.f; }

    const int srow = tid >> 3;
    const int skq  = (tid & 7) * 4;
    int sgrow = row0 + srow; if (sgrow >= N) sgrow = N - 1;

    const unsigned short* WtV = Wt + (size_t)8 * 256 * 32;

    for (int ks = 0; ks < F / KSTEP; ++ks) {
        const int k0 = ks * KSTEP;
        {
            const float4 am = *(const float4*)&mean[(size_t)sgrow * F + k0 + skq];
            const float4 av = *(const float4*)&var [(size_t)sgrow * F + k0 + skq];
            ushort4 um = { f2b(am.x), f2b(am.y), f2b(am.z), f2b(am.w) };
            ushort4 uv = { f2b(av.x), f2b(av.y), f2b(av.z), f2b(av.w) };
            *(ushort4*)&Asm[srow][skq] = um;
            *(ushort4*)&Asv[srow][skq] = uv;
        }
        {
            const unsigned short* sm = Wt  + (size_t)(ks * 256) * 32;
            const unsigned short* sv = WtV + (size_t)(ks * 256) * 32;
            #pragma unroll
            for (int h = 0; h < 2; ++h) {
                int c = tid + h * 512;
                int n = c >> 2, q = c & 3;
                *(ushort8v*)&Bsm[n][q * 8] = *(const ushort8v*)(sm + (size_t)n * 32 + q * 8);
                *(ushort8v*)&Bsv[n][q * 8] = *(const ushort8v*)(sv + (size_t)n * 32 + q * 8);
            }
        }
        __syncthreads();

        bhalf8 am0 = *(const bhalf8*)&Asm[wr*32 +  0 + lr][lk*8];
        bhalf8 am1 = *(const bhalf8*)&Asm[wr*32 + 16 + lr][lk*8];
        bhalf8 av0 = *(const bhalf8*)&Asv[wr*32 +  0 + lr][lk*8];
        bhalf8 av1 = *(const bhalf8*)&Asv[wr*32 + 16 + lr][lk*8];
        #pragma unroll
        for (int ct = 0; ct < 4; ++ct) {
            bhalf8 bmf = *(const bhalf8*)&Bsm[wc*64 + ct*16 + lr][lk*8];
            bhalf8 bvf = *(const bhalf8*)&Bsv[wc*64 + ct*16 + lr][lk*8];
            accm[0][ct] = __builtin_amdgcn_mfma_f32_16x16x32_bf16(am0, bmf, accm[0][ct], 0, 0, 0);
            accm[1][ct] = __builtin_amdgcn_mfma_f32_16x16x32_bf16(am1, bmf, accm[1][ct], 0, 0, 0);
            accv[0][ct] = __builtin_amdgcn_mfma_f32_16x16x32_bf16(av0, bvf, accv[0][ct], 0, 0, 0);
            accv[1][ct] = __builtin_amdgcn_mfma_f32_16x16x32_bf16(av1, bvf, accv[1][ct], 0, 0, 0);
        }
        __syncthreads();
    }

    #pragma unroll
    for (int rt = 0; rt < 2; ++rt) {
        #pragma unroll
        for (int ct = 0; ct < 4; ++ct) {
            const int col = wc*64 + ct*16 + lr;
            const float bmc = bm[col], bvc = bv[col];
            #pragma unroll
            for (int q = 0; q < 4; ++q) {
                int grow = row0 + wr*32 + rt*16 + lk*4 + q;
                if (grow < N) {
                    float mp = accm[rt][ct][q] + bmc;
                    float vp = accv[rt][ct][q] + bvc;
                    float me = mp > 0.f ? mp : (__expf(mp) - 1.f);
                    float vr = vp > 0.f ? vp : 0.f;
                    float att = __expf(-vr);
                    mv[(size_t)grow * 512 + col]       = f2b(me * att);
                    mv[(size_t)grow * 512 + 256 + col] = f2b(vr * att * att);
                }
            }
        }
    }
}

// ---------------------------------------------------------------------------
// dense + bucket-fill interleaved (4 fill : 1 dense).
// fill: slot = atomicAdd(count[r]); 8-byte record {col, v1:bf16<<16|v0:bf16}.
// ---------------------------------------------------------------------------
__global__ __launch_bounds__(512) void dense_fill_bucket_kernel(
    const float* __restrict__ mean, const float* __restrict__ var,
    const unsigned short* __restrict__ Wt,
    const float* __restrict__ bm, const float* __restrict__ bv,
    unsigned short* __restrict__ mv, int N, int DB,
    const int* __restrict__ erow, const int* __restrict__ ecol,
    const float* __restrict__ a0, const float* __restrict__ a1,
    int E, int* __restrict__ count, u32x2* __restrict__ slots,
    int* __restrict__ ovcnt, i32x4* __restrict__ ovlist)
{
    __shared__ unsigned short Asm[64][40];
    __shared__ unsigned short Asv[64][40];
    __shared__ unsigned short Bsm[256][40];
    __shared__ unsigned short Bsv[256][40];

    const int g = blockIdx.x / 5;
    const int r = blockIdx.x % 5;

    if (r != 4) {
        int i = (g * 4 + r) * 512 + threadIdx.x;
        if (i < E) {
            int   rr = erow[i];
            int   c  = ecol[i];
            float v0 = a0[i];
            float v1 = a1[i];
            int pos = atomicAdd(&count[rr], 1);
            if (pos < CAP) {
                u32x2 rc;
                rc[0] = (unsigned)c;
                rc[1] = (unsigned)f2b(v0) | ((unsigned)f2b(v1) << 16);
                slots[(size_t)rr * CAP + pos] = rc;
            } else {
                int o = atomicAdd(ovcnt, 1);
                if (o < OVMAX) {
                    i32x4 rc;
                    rc[0] = rr;
                    rc[1] = c;
                    rc[2] = __float_as_int(v0);
                    rc[3] = __float_as_int(v1);
                    ovlist[o] = rc;
                }
            }
        }
        return;
    }
    if (g >= DB) return;
    dense_tile(mean, var, Wt, bm, bv, mv, N, g, Asm, Asv, Bsm, Bsv);
}

// ---------------------------------------------------------------------------
// spmm: 1 wave per node; degree = min(count[node], CAP); 8-deep gather
// batches with next-batch record prefetch. 8-byte records.
// ---------------------------------------------------------------------------
__global__ __launch_bounds__(256) void spmm_bucket_kernel(
    const int* __restrict__ count, const u32x2* __restrict__ slots,
    const unsigned short* __restrict__ mv,
    float* __restrict__ out, int N)
{
    int w    = threadIdx.x >> 6;
    int lane = threadIdx.x & 63;
    int node = blockIdx.x * 4 + w;
    if (node >= N) return;
    int cnt = count[node];
    if (cnt > CAP) cnt = CAP;

    const bool isv = lane >= 32;
    const int  fb  = (lane & 31) * 8;
    const unsigned short* base = mv + (isv ? 256 : 0) + fb;
    const int sh = isv ? 16 : 0;

    float acc[8];
    #pragma unroll
    for (int q = 0; q < 8; ++q) acc[q] = 0.f;

    const int nb  = cnt >> 3;
    const u32x2* rp  = slots + (size_t)node * CAP;
    const u32x2* rp0 = rp;

    if (nb > 0) {
        int   c[8];
        float wt[8];
        #pragma unroll
        for (int q = 0; q < 8; ++q) {
            u32x2 rc = __builtin_nontemporal_load(rp + q);
            c[q]  = (int)rc[0];
            wt[q] = b2f((unsigned short)(rc[1] >> sh));
        }
        for (int b = 0; b < nb; ++b) {
            ushort8v p[8];
            #pragma unroll
            for (int q = 0; q < 8; ++q)
                p[q] = *(const ushort8v*)(base + (size_t)c[q] * 512);
            int   cn[8];
            float wn[8];
            if (b + 1 < nb) {
                const u32x2* rn = rp + 8;
                #pragma unroll
                for (int q = 0; q < 8; ++q) {
                    u32x2 rc = __builtin_nontemporal_load(rn + q);
                    cn[q] = (int)rc[0];
                    wn[q] = b2f((unsigned short)(rc[1] >> sh));
                }
            }
            #pragma unroll
            for (int q = 0; q < 8; ++q) {
                #pragma unroll
                for (int t = 0; t < 8; ++t) acc[t] += wt[q] * b2f(p[q][t]);
            }
            #pragma unroll
            for (int q = 0; q < 8; ++q) { c[q] = cn[q]; wt[q] = wn[q]; }
            rp += 8;
        }
    }
    for (int j = nb * 8; j < cnt; ++j) {
        u32x2 rc = rp0[j];
        int   cc = (int)rc[0];
        float a  = b2f((unsigned short)(rc[1] >> sh));
        ushort8v p = *(const ushort8v*)(base + (size_t)cc * 512);
        #pragma unroll
        for (int t = 0; t < 8; ++t) acc[t] += a * b2f(p[t]);
    }

    float* obase = out + (isv ? (size_t)N * F : 0) + (size_t)node * F + fb;
    float4 o0 = { acc[0], acc[1], acc[2], acc[3] };
    float4 o1 = { acc[4], acc[5], acc[6], acc[7] };
    *(float4*)obase       = o0;
    *(float4*)(obase + 4) = o1;
}

// ---------------------------------------------------------------------------
// overflow: one wave per overflow edge, atomicAdd into out (expected ~0).
// ---------------------------------------------------------------------------
__global__ __launch_bounds__(256) void overflow_kernel(
    const int* __restrict__ ovcnt, const i32x4* __restrict__ ovlist,
    const unsigned short* __restrict__ mv, float* __restrict__ out, int N)
{
    int nov = *ovcnt;
    if (nov > OVMAX) nov = OVMAX;
    if (nov == 0) return;
    int gw   = (blockIdx.x * 256 + threadIdx.x) >> 6;
    int nw   = (gridDim.x * 256) >> 6;
    int lane = threadIdx.x & 63;
    const bool isv = lane >= 32;
    const int  fb  = (lane & 31) * 8;
    for (int e = gw; e < nov; e += nw) {
        i32x4 rc = ovlist[e];
        int row = rc[0], c = rc[1];
        float a = __int_as_float(isv ? rc[3] : rc[2]);
        const unsigned short* p = mv + (size_t)c * 512 + (isv ? 256 : 0) + fb;
        float* ob = out + (isv ? (size_t)N * F : 0) + (size_t)row * F + fb;
        #pragma unroll
        for (int t = 0; t < 8; ++t)
            atomicAdd(&ob[t], a * b2f(p[t]));
    }
}

// ---------------------------------------------------------------------------
extern "C" void kernel_launch(void* const* d_in, const int* in_sizes, int n_in,
                              void* d_out, int out_size, void* d_ws, size_t ws_size,
                              hipStream_t stream)
{
    const float* mean = (const float*)d_in[0];
    const float* var  = (const float*)d_in[1];
    const float* Wm   = (const float*)d_in[2];
    const float* bm   = (const float*)d_in[3];
    const float* Wv   = (const float*)d_in[4];
    const float* bv   = (const float*)d_in[5];
    const int*   erow = (const int*)d_in[6];
    const int*   ecol = (const int*)d_in[7];
    const float* a0   = (const float*)d_in[8];
    const float* a1   = (const float*)d_in[9];

    const int N = in_sizes[0] / F;     // 100000
    const int E = in_sizes[6];         // 3200000

    const int DB = (N + 63) / 64;            // 1563 dense tiles
    const int FB = (E + 511) / 512;          // 6250 fill blocks
    int groups = (DB > (FB + 3) / 4) ? DB : (FB + 3) / 4;
    int total  = groups * 5;

    uintptr_t p = (uintptr_t)d_ws;
    auto take = [&](size_t bytes) {
        uintptr_t r = (p + 255) & ~(uintptr_t)255;
        p = r + bytes;
        return (void*)r;
    };

    unsigned short* mv     = (unsigned short*)take((size_t)N * 512 * 2);
    u32x2*          slots  = (u32x2*)take((size_t)N * CAP * 8);
    int*            count  = (int*)take((size_t)N * 4);
    int*            ovcnt  = (int*)take(256);
    i32x4*          ovlist = (i32x4*)take((size_t)OVMAX * 16);
    unsigned short* Wt     = (unsigned short*)take((size_t)2 * 8 * 256 * 32 * 2);

    setup_kernel<<<114, 256, 0, stream>>>(Wm, Wv, Wt, count, ovcnt, N);
    dense_fill_bucket_kernel<<<total, 512, 0, stream>>>(
        mean, var, Wt, bm, bv, mv, N, DB,
        erow, ecol, a0, a1, E, count, slots, ovcnt, ovlist);
    spmm_bucket_kernel<<<(N + 3) / 4, 256, 0, stream>>>(
        count, slots, mv, (float*)d_out, N);
    overflow_kernel<<<16, 256, 0, stream>>>(ovcnt, ovlist, mv, (float*)d_out, N);
}

// Round 11
// 657.703 us; speedup vs baseline: 1.0317x; 1.0317x over previous
//
#include <hip/hip_runtime.h>
#include <hip/hip_bf16.h>
#include <stdint.h>

#define F 256            // IN_F == OUT_F == 256
#define KSTEP 32
#define CAP 64           // bucket slots per node (Poisson(32): P(deg>=64)~2e-7)
#define OVMAX 200000     // overflow list capacity

typedef short bhalf8 __attribute__((ext_vector_type(8)));
typedef unsigned short ushort8v __attribute__((ext_vector_type(8)));
typedef float f32x4 __attribute__((ext_vector_type(4)));
typedef int i32x4 __attribute__((ext_vector_type(4)));
typedef unsigned int u32x2 __attribute__((ext_vector_type(2)));

__device__ __forceinline__ unsigned short f2b(float f) {
    union { float f; uint32_t u; } x; x.f = f;
    uint32_t u = x.u;
    return (unsigned short)((u + 0x7FFFu + ((u >> 16) & 1u)) >> 16);
}
__device__ __forceinline__ float b2f(unsigned short h) {
    union { uint32_t u; float f; } x; x.u = ((uint32_t)h) << 16;
    return x.f;
}
// pack 2 f32 -> 2 bf16 (RNE) in one VALU op
__device__ __forceinline__ unsigned int cvtpk(float lo, float hi) {
    unsigned int r;
    asm("v_cvt_pk_bf16_f32 %0, %1, %2" : "=v"(r) : "v"(lo), "v"(hi));
    return r;
}

// ---------------------------------------------------------------------------
// setup: blocks [0,98) zero count (+ overflow counter); [98,114) W-prep
// ---------------------------------------------------------------------------
__global__ __launch_bounds__(256) void setup_kernel(
    const float* __restrict__ Wm, const float* __restrict__ Wv,
    unsigned short* __restrict__ Wt, int* __restrict__ count,
    int* __restrict__ ovcnt, int N)
{
    if (blockIdx.x < 98) {
        if (blockIdx.x == 0 && threadIdx.x == 0) *ovcnt = 0;
        int gi = blockIdx.x * 1024 + threadIdx.x * 4;
        #pragma unroll
        for (int q = 0; q < 4; ++q)
            if (gi + q < N) count[gi + q] = 0;
        return;
    }
    int idx = (blockIdx.x - 98) * 256 + threadIdx.x;
    int sel = idx >> 11;
    int ks  = (idx >> 8) & 7;
    int n   = idx & 255;
    const float* W = sel ? Wv : Wm;
    unsigned short* dst = Wt + ((size_t)sel * 8 * 256 * 32) + ((size_t)(ks * 256 + n) * 32);
    #pragma unroll
    for (int kk = 0; kk < 32; ++kk)
        dst[kk] = f2b(W[(ks * 32 + kk) * 256 + n]);
}

// ---------------------------------------------------------------------------
// Dense tile body (R2-proven double-staged; A-convert via v_cvt_pk_bf16_f32).
// ---------------------------------------------------------------------------
__device__ __forceinline__ void dense_tile(
    const float* __restrict__ mean, const float* __restrict__ var,
    const unsigned short* __restrict__ Wt,
    const float* __restrict__ bm, const float* __restrict__ bv,
    unsigned short* __restrict__ mv, int N, int dbid,
    unsigned short (*Asm)[40], unsigned short (*Asv)[40],
    unsigned short (*Bsm)[40], unsigned short (*Bsv)[40])
{
    const int tid  = threadIdx.x;
    const int row0 = dbid * 64;
    const int lane = tid & 63;
    const int w    = tid >> 6;
    const int wr   = w >> 2;
    const int wc   = w & 3;
    const int lr   = lane & 15;
    const int lk   = lane >> 4;

    f32x4 accm[2][4], accv[2][4];
    #pragma unroll
    for (int i = 0; i < 2; ++i)
        #pragma unroll
        for (int j = 0; j < 4; ++j) { accm[i][j] = (f32x4)0.f; accv[i][j] = (f32x4)0.f; }

    const int srow = tid >> 3;
    const int skq  = (tid & 7) * 4;
    int sgrow = row0 + srow; if (sgrow >= N) sgrow = N - 1;

    const unsigned short* WtV = Wt + (size_t)8 * 256 * 32;

    for (int ks = 0; ks < F / KSTEP; ++ks) {
        const int k0 = ks * KSTEP;
        {
            const float4 am = *(const float4*)&mean[(size_t)sgrow * F + k0 + skq];
            const float4 av = *(const float4*)&var [(size_t)sgrow * F + k0 + skq];
            u32x2 um = { cvtpk(am.x, am.y), cvtpk(am.z, am.w) };
            u32x2 uv = { cvtpk(av.x, av.y), cvtpk(av.z, av.w) };
            *(u32x2*)&Asm[srow][skq] = um;
            *(u32x2*)&Asv[srow][skq] = uv;
        }
        {
            const unsigned short* sm = Wt  + (size_t)(ks * 256) * 32;
            const unsigned short* sv = WtV + (size_t)(ks * 256) * 32;
            #pragma unroll
            for (int h = 0; h < 2; ++h) {
                int c = tid + h * 512;
                int n = c >> 2, q = c & 3;
                *(ushort8v*)&Bsm[n][q * 8] = *(const ushort8v*)(sm + (size_t)n * 32 + q * 8);
                *(ushort8v*)&Bsv[n][q * 8] = *(const ushort8v*)(sv + (size_t)n * 32 + q * 8);
            }
        }
        __syncthreads();

        bhalf8 am0 = *(const bhalf8*)&Asm[wr*32 +  0 + lr][lk*8];
        bhalf8 am1 = *(const bhalf8*)&Asm[wr*32 + 16 + lr][lk*8];
        bhalf8 av0 = *(const bhalf8*)&Asv[wr*32 +  0 + lr][lk*8];
        bhalf8 av1 = *(const bhalf8*)&Asv[wr*32 + 16 + lr][lk*8];
        #pragma unroll
        for (int ct = 0; ct < 4; ++ct) {
            bhalf8 bmf = *(const bhalf8*)&Bsm[wc*64 + ct*16 + lr][lk*8];
            bhalf8 bvf = *(const bhalf8*)&Bsv[wc*64 + ct*16 + lr][lk*8];
            accm[0][ct] = __builtin_amdgcn_mfma_f32_16x16x32_bf16(am0, bmf, accm[0][ct], 0, 0, 0);
            accm[1][ct] = __builtin_amdgcn_mfma_f32_16x16x32_bf16(am1, bmf, accm[1][ct], 0, 0, 0);
            accv[0][ct] = __builtin_amdgcn_mfma_f32_16x16x32_bf16(av0, bvf, accv[0][ct], 0, 0, 0);
            accv[1][ct] = __builtin_amdgcn_mfma_f32_16x16x32_bf16(av1, bvf, accv[1][ct], 0, 0, 0);
        }
        __syncthreads();
    }

    #pragma unroll
    for (int rt = 0; rt < 2; ++rt) {
        #pragma unroll
        for (int ct = 0; ct < 4; ++ct) {
            const int col = wc*64 + ct*16 + lr;
            const float bmc = bm[col], bvc = bv[col];
            #pragma unroll
            for (int q = 0; q < 4; ++q) {
                int grow = row0 + wr*32 + rt*16 + lk*4 + q;
                if (grow < N) {
                    float mp = accm[rt][ct][q] + bmc;
                    float vp = accv[rt][ct][q] + bvc;
                    float me = mp > 0.f ? mp : (__expf(mp) - 1.f);
                    float vr = vp > 0.f ? vp : 0.f;
                    float att = __expf(-vr);
                    mv[(size_t)grow * 512 + col]       = f2b(me * att);
                    mv[(size_t)grow * 512 + 256 + col] = f2b(vr * att * att);
                }
            }
        }
    }
}

// ---------------------------------------------------------------------------
// dense + bucket-fill interleaved (2 fill : 1 dense); fill = 2 edges/thread.
// 16-byte record {col, v0:f32, v1:f32, 0} (R8-proven layout).
// ---------------------------------------------------------------------------
__global__ __launch_bounds__(512) void dense_fill_bucket_kernel(
    const float* __restrict__ mean, const float* __restrict__ var,
    const unsigned short* __restrict__ Wt,
    const float* __restrict__ bm, const float* __restrict__ bv,
    unsigned short* __restrict__ mv, int N, int DB,
    const int* __restrict__ erow, const int* __restrict__ ecol,
    const float* __restrict__ a0, const float* __restrict__ a1,
    int E, int* __restrict__ count, i32x4* __restrict__ slots,
    int* __restrict__ ovcnt, i32x4* __restrict__ ovlist)
{
    __shared__ unsigned short Asm[64][40];
    __shared__ unsigned short Asv[64][40];
    __shared__ unsigned short Bsm[256][40];
    __shared__ unsigned short Bsv[256][40];

    const int g = blockIdx.x / 3;
    const int r = blockIdx.x % 3;

    if (r != 2) {
        // ---- fill: 2 edges per thread, vectorized edge reads
        int i = ((g * 2 + r) * 512 + threadIdx.x) * 2;
        if (i + 1 < E) {
            int2   rr = *(const int2*)&erow[i];
            int2   cc = *(const int2*)&ecol[i];
            float2 v0 = *(const float2*)&a0[i];
            float2 v1 = *(const float2*)&a1[i];
            #pragma unroll
            for (int e = 0; e < 2; ++e) {
                int rrr = e ? rr.y : rr.x;
                int ccc = e ? cc.y : cc.x;
                float w0 = e ? v0.y : v0.x;
                float w1 = e ? v1.y : v1.x;
                int pos = atomicAdd(&count[rrr], 1);
                if (pos < CAP) {
                    i32x4 rc;
                    rc[0] = ccc;
                    rc[1] = __float_as_int(w0);
                    rc[2] = __float_as_int(w1);
                    rc[3] = 0;
                    slots[(size_t)rrr * CAP + pos] = rc;
                } else {
                    int o = atomicAdd(ovcnt, 1);
                    if (o < OVMAX) {
                        i32x4 rc;
                        rc[0] = rrr;
                        rc[1] = ccc;
                        rc[2] = __float_as_int(w0);
                        rc[3] = __float_as_int(w1);
                        ovlist[o] = rc;
                    }
                }
            }
        } else if (i < E) {
            int   rrr = erow[i];
            int   ccc = ecol[i];
            float w0  = a0[i];
            float w1  = a1[i];
            int pos = atomicAdd(&count[rrr], 1);
            if (pos < CAP) {
                i32x4 rc;
                rc[0] = ccc;
                rc[1] = __float_as_int(w0);
                rc[2] = __float_as_int(w1);
                rc[3] = 0;
                slots[(size_t)rrr * CAP + pos] = rc;
            } else {
                int o = atomicAdd(ovcnt, 1);
                if (o < OVMAX) {
                    i32x4 rc;
                    rc[0] = rrr;
                    rc[1] = ccc;
                    rc[2] = __float_as_int(w0);
                    rc[3] = __float_as_int(w1);
                    ovlist[o] = rc;
                }
            }
        }
        return;
    }
    if (g >= DB) return;
    dense_tile(mean, var, Wt, bm, bv, mv, N, g, Asm, Asv, Bsm, Bsv);
}

// ---------------------------------------------------------------------------
// spmm (R8-proven): 1 wave per node; 8-deep gather batches with next-batch
// record prefetch; 16-byte records.
// ---------------------------------------------------------------------------
__global__ __launch_bounds__(256) void spmm_bucket_kernel(
    const int* __restrict__ count, const int* __restrict__ slots,
    const unsigned short* __restrict__ mv,
    float* __restrict__ out, int N)
{
    int w    = threadIdx.x >> 6;
    int lane = threadIdx.x & 63;
    int node = blockIdx.x * 4 + w;
    if (node >= N) return;
    int cnt = count[node];
    if (cnt > CAP) cnt = CAP;

    const bool isv = lane >= 32;
    const int  fb  = (lane & 31) * 8;
    const unsigned short* base = mv + (isv ? 256 : 0) + fb;
    const int woff = isv ? 2 : 1;

    float acc[8];
    #pragma unroll
    for (int q = 0; q < 8; ++q) acc[q] = 0.f;

    const int nb  = cnt >> 3;
    const int* rp  = slots + (size_t)node * CAP * 4;
    const int* rp0 = rp;

    if (nb > 0) {
        int   c[8];
        float wt[8];
        #pragma unroll
        for (int q = 0; q < 8; ++q) {
            c[q]  = __builtin_nontemporal_load(rp + q * 4);
            wt[q] = __int_as_float(__builtin_nontemporal_load(rp + q * 4 + woff));
        }
        for (int b = 0; b < nb; ++b) {
            ushort8v p[8];
            #pragma unroll
            for (int q = 0; q < 8; ++q)
                p[q] = *(const ushort8v*)(base + (size_t)c[q] * 512);
            int   cn[8];
            float wn[8];
            if (b + 1 < nb) {
                const int* rn = rp + 32;
                #pragma unroll
                for (int q = 0; q < 8; ++q) {
                    cn[q] = __builtin_nontemporal_load(rn + q * 4);
                    wn[q] = __int_as_float(__builtin_nontemporal_load(rn + q * 4 + woff));
                }
            }
            #pragma unroll
            for (int q = 0; q < 8; ++q) {
                #pragma unroll
                for (int t = 0; t < 8; ++t) acc[t] += wt[q] * b2f(p[q][t]);
            }
            #pragma unroll
            for (int q = 0; q < 8; ++q) { c[q] = cn[q]; wt[q] = wn[q]; }
            rp += 32;
        }
    }
    for (int j = nb * 8; j < cnt; ++j) {
        const int* rj = rp0 + (size_t)j * 4;
        int   cc = rj[0];
        float a  = __int_as_float(rj[woff]);
        ushort8v p = *(const ushort8v*)(base + (size_t)cc * 512);
        #pragma unroll
        for (int t = 0; t < 8; ++t) acc[t] += a * b2f(p[t]);
    }

    float* obase = out + (isv ? (size_t)N * F : 0) + (size_t)node * F + fb;
    float4 o0 = { acc[0], acc[1], acc[2], acc[3] };
    float4 o1 = { acc[4], acc[5], acc[6], acc[7] };
    *(float4*)obase       = o0;
    *(float4*)(obase + 4) = o1;
}

// ---------------------------------------------------------------------------
// overflow: one wave per overflow edge, atomicAdd into out (expected ~0).
// ---------------------------------------------------------------------------
__global__ __launch_bounds__(256) void overflow_kernel(
    const int* __restrict__ ovcnt, const i32x4* __restrict__ ovlist,
    const unsigned short* __restrict__ mv, float* __restrict__ out, int N)
{
    int nov = *ovcnt;
    if (nov > OVMAX) nov = OVMAX;
    if (nov == 0) return;
    int gw   = (blockIdx.x * 256 + threadIdx.x) >> 6;
    int nw   = (gridDim.x * 256) >> 6;
    int lane = threadIdx.x & 63;
    const bool isv = lane >= 32;
    const int  fb  = (lane & 31) * 8;
    for (int e = gw; e < nov; e += nw) {
        i32x4 rc = ovlist[e];
        int row = rc[0], c = rc[1];
        float a = __int_as_float(isv ? rc[3] : rc[2]);
        const unsigned short* p = mv + (size_t)c * 512 + (isv ? 256 : 0) + fb;
        float* ob = out + (isv ? (size_t)N * F : 0) + (size_t)row * F + fb;
        #pragma unroll
        for (int t = 0; t < 8; ++t)
            atomicAdd(&ob[t], a * b2f(p[t]));
    }
}

// ---------------------------------------------------------------------------
extern "C" void kernel_launch(void* const* d_in, const int* in_sizes, int n_in,
                              void* d_out, int out_size, void* d_ws, size_t ws_size,
                              hipStream_t stream)
{
    const float* mean = (const float*)d_in[0];
    const float* var  = (const float*)d_in[1];
    const float* Wm   = (const float*)d_in[2];
    const float* bm   = (const float*)d_in[3];
    const float* Wv   = (const float*)d_in[4];
    const float* bv   = (const float*)d_in[5];
    const int*   erow = (const int*)d_in[6];
    const int*   ecol = (const int*)d_in[7];
    const float* a0   = (const float*)d_in[8];
    const float* a1   = (const float*)d_in[9];

    const int N = in_sizes[0] / F;     // 100000
    const int E = in_sizes[6];         // 3200000

    const int DB = (N + 63) / 64;             // 1563 dense tiles
    const int FB = (E + 1023) / 1024;         // 3125 fill blocks (2 edges/thr)
    int groups = (DB > (FB + 1) / 2) ? DB : (FB + 1) / 2;
    int total  = groups * 3;

    uintptr_t p = (uintptr_t)d_ws;
    auto take = [&](size_t bytes) {
        uintptr_t r = (p + 255) & ~(uintptr_t)255;
        p = r + bytes;
        return (void*)r;
    };

    unsigned short* mv     = (unsigned short*)take((size_t)N * 512 * 2);
    i32x4*          slots  = (i32x4*)take((size_t)N * CAP * 16);
    int*            count  = (int*)take((size_t)N * 4);
    int*            ovcnt  = (int*)take(256);
    i32x4*          ovlist = (i32x4*)take((size_t)OVMAX * 16);
    unsigned short* Wt     = (unsigned short*)take((size_t)2 * 8 * 256 * 32 * 2);

    setup_kernel<<<114, 256, 0, stream>>>(Wm, Wv, Wt, count, ovcnt, N);
    dense_fill_bucket_kernel<<<total, 512, 0, stream>>>(
        mean, var, Wt, bm, bv, mv, N, DB,
        erow, ecol, a0, a1, E, count, slots, ovcnt, ovlist);
    spmm_bucket_kernel<<<(N + 3) / 4, 256, 0, stream>>>(
        count, (const int*)slots, mv, (float*)d_out, N);
    overflow_kernel<<<16, 256, 0, stream>>>(ovcnt, ovlist, mv, (float*)d_out, N);
}